// Round 1
// baseline (3616.042 us; speedup 1.0000x reference)
//
#include <hip/hip_runtime.h>
#include <math.h>

#define EPSF 1e-8f

constexpr int CB = 16;      // batch
constexpr int CT = 1024;    // time
constexpr int CN = 512;     // nodes
constexpr int CD = 512;     // hidden
constexpr int CIN = 1536;   // 3*N
constexpr int PB = CN * CN;                 // 262144 per-batch matrix elems
constexpr size_t SBTN = (size_t)CB * CT * CN;   // 8,388,608
constexpr size_t SBNN = (size_t)CB * PB;        // 4,194,304

// ---------------- utility ----------------
__global__ void zero_k(float* p, int n) {
  int i = blockIdx.x * 256 + threadIdx.x;
  if (i < n) p[i] = 0.f;
}

// ---------------- column means + centering ----------------
__global__ __launch_bounds__(256) void colmean_k(const float* __restrict__ x, float* __restrict__ ms) {
  int b = blockIdx.y;
  int n = blockIdx.x * 256 + threadIdx.x;
  int t0 = blockIdx.z * 256;
  const float* xb = x + (size_t)b * CT * CN + (size_t)t0 * CN + n;
  float s = 0.f;
  for (int t = 0; t < 256; ++t) s += xb[(size_t)t * CN];
  atomicAdd(&ms[b * CN + n], s);
}

__global__ __launch_bounds__(256) void center_k(const float* __restrict__ x, const float* __restrict__ ms,
                                                float* __restrict__ xm) {
  size_t e = (size_t)blockIdx.x * 256 + threadIdx.x;
  int b = (int)(e >> 19);          // T*N = 2^19
  int n = (int)(e & (CN - 1));
  xm[e] = x[e] - ms[b * CN + n] * (1.0f / CT);
}

// ---------------- Spearman ranks (stable, exact tie semantics) ----------------
// key = (sortable_u32(x) << 10) | t  -> all keys distinct -> rank = #{K_j < K_t}
__global__ __launch_bounds__(256) void ranks_k(const float* __restrict__ x, float* __restrict__ rm) {
  int b = blockIdx.y;
  int n0 = blockIdx.x * 4;
  __shared__ unsigned long long ks[1024][4];   // 32 KB
  const float* xb = x + (size_t)b * CT * CN;
  for (int idx = threadIdx.x; idx < 4096; idx += 256) {
    int t = idx >> 2, cc = idx & 3;
    float v = xb[(size_t)t * CN + n0 + cc];
    unsigned int u = __float_as_uint(v);
    u = (u & 0x80000000u) ? ~u : (u | 0x80000000u);
    ks[t][cc] = (((unsigned long long)u) << 10) | (unsigned int)t;
  }
  __syncthreads();
  int c = threadIdx.x >> 6;       // wave -> one column (broadcast LDS reads)
  int sub = threadIdx.x & 63;
  float* rmb = rm + (size_t)b * CT * CN + n0 + c;
  for (int m = 0; m < 4; ++m) {
    int t0 = sub + 64 * (4 * m + 0);
    int t1 = sub + 64 * (4 * m + 1);
    int t2 = sub + 64 * (4 * m + 2);
    int t3 = sub + 64 * (4 * m + 3);
    unsigned long long K0 = ks[t0][c], K1 = ks[t1][c], K2 = ks[t2][c], K3 = ks[t3][c];
    int c0 = 0, c1 = 0, c2 = 0, c3 = 0;
    for (int j = 0; j < 1024; ++j) {
      unsigned long long kj = ks[j][c];
      c0 += (kj < K0); c1 += (kj < K1); c2 += (kj < K2); c3 += (kj < K3);
    }
    rmb[(size_t)t0 * CN] = (float)(c0 + 1) - 512.5f;
    rmb[(size_t)t1 * CN] = (float)(c1 + 1) - 512.5f;
    rmb[(size_t)t2 * CN] = (float)(c2 + 1) - 512.5f;
    rmb[(size_t)t3 * CN] = (float)(c3 + 1) - 512.5f;
  }
}

// ---------------- generic fp32 tiled GEMM ----------------
// C = alpha * op(A) * op(B) [+ C if ACC] [+ bias] [relu]
// TA: A stored (K x M) row-major (lda = row stride). else (M x K).
// TB: B stored (N x K) row-major (ldb = row stride). else (K x N).
template<bool TA, bool TB, bool ACC, bool RELU>
__global__ __launch_bounds__(256) void gemm_k(
    const float* __restrict__ A, const float* __restrict__ B,
    const float* __restrict__ bias, float* __restrict__ C,
    int M, int Nc, int K, int lda, int ldb, int ldc,
    long long sA, long long sB, long long sC, float alpha) {
  __shared__ float As[16][68];
  __shared__ float Bs[16][68];
  const int bz = blockIdx.z;
  A += (size_t)bz * sA;
  B += (size_t)bz * sB;
  C += (size_t)bz * sC;
  const int n0 = blockIdx.x * 64;
  const int m0 = blockIdx.y * 64;
  const int tid = threadIdx.x;
  const int tn = (tid & 15) * 4;
  const int tm = (tid >> 4) * 4;
  float acc[4][4];
#pragma unroll
  for (int i = 0; i < 4; ++i)
#pragma unroll
    for (int j = 0; j < 4; ++j) acc[i][j] = 0.f;

  for (int k0 = 0; k0 < K; k0 += 16) {
    if (TA) {
      const int lk = tid >> 4;
      const int lm = (tid & 15) * 4;
      const float4 v = *(const float4*)&A[(size_t)(k0 + lk) * lda + m0 + lm];
      *(float4*)&As[lk][lm] = v;
    } else {
      const int lm = tid >> 2;
      const int lk = (tid & 3) * 4;
      const float4 v = *(const float4*)&A[(size_t)(m0 + lm) * lda + k0 + lk];
      As[lk + 0][lm] = v.x; As[lk + 1][lm] = v.y; As[lk + 2][lm] = v.z; As[lk + 3][lm] = v.w;
    }
    if (TB) {
      const int ln = tid >> 2;
      const int lk = (tid & 3) * 4;
      const float4 v = *(const float4*)&B[(size_t)(n0 + ln) * ldb + k0 + lk];
      Bs[lk + 0][ln] = v.x; Bs[lk + 1][ln] = v.y; Bs[lk + 2][ln] = v.z; Bs[lk + 3][ln] = v.w;
    } else {
      const int lk = tid >> 4;
      const int ln = (tid & 15) * 4;
      const float4 v = *(const float4*)&B[(size_t)(k0 + lk) * ldb + n0 + ln];
      *(float4*)&Bs[lk][ln] = v;
    }
    __syncthreads();
#pragma unroll
    for (int kk = 0; kk < 16; ++kk) {
      const float4 a4 = *(const float4*)&As[kk][tm];
      const float4 b4 = *(const float4*)&Bs[kk][tn];
      const float av[4] = {a4.x, a4.y, a4.z, a4.w};
      const float bv[4] = {b4.x, b4.y, b4.z, b4.w};
#pragma unroll
      for (int i = 0; i < 4; ++i)
#pragma unroll
        for (int j = 0; j < 4; ++j) acc[i][j] = fmaf(av[i], bv[j], acc[i][j]);
    }
    __syncthreads();
  }
  float4 bb = make_float4(0.f, 0.f, 0.f, 0.f);
  if (bias) bb = *(const float4*)&bias[n0 + tn];
#pragma unroll
  for (int i = 0; i < 4; ++i) {
    size_t off = (size_t)(m0 + tm + i) * ldc + (n0 + tn);
    float4 v;
    v.x = alpha * acc[i][0] + bb.x;
    v.y = alpha * acc[i][1] + bb.y;
    v.z = alpha * acc[i][2] + bb.z;
    v.w = alpha * acc[i][3] + bb.w;
    if (ACC) {
      const float4 c0 = *(const float4*)&C[off];
      v.x += c0.x; v.y += c0.y; v.z += c0.z; v.w += c0.w;
    }
    if (RELU) {
      v.x = fmaxf(v.x, 0.f); v.y = fmaxf(v.y, 0.f);
      v.z = fmaxf(v.z, 0.f); v.w = fmaxf(v.w, 0.f);
    }
    *(float4*)&C[off] = v;
  }
}

// ---------------- std vectors ----------------
__global__ void sds_k(const float* __restrict__ covx, const float* __restrict__ covr,
                      float* __restrict__ sdx, float* __restrict__ sdr) {
  int idx = blockIdx.x * 256 + threadIdx.x;     // < CB*CN
  int b = idx >> 9, i = idx & (CN - 1);
  size_t off = (size_t)b * PB + (size_t)i * (CN + 1);
  sdx[idx] = sqrtf(fmaxf(covx[off], EPSF));
  sdr[idx] = sqrtf(fmaxf(covr[off], EPSF));
}

__global__ void ridge_k(const float* __restrict__ covx, float* __restrict__ A) {
  size_t e = (size_t)blockIdx.x * 256 + threadIdx.x;  // < SBNN
  int ij = (int)(e & (PB - 1));
  int i = ij >> 9, j = ij & (CN - 1);
  A[e] = covx[e] + ((i == j) ? 0.001f : 0.0f);
}

// ---------------- blocked Cholesky pieces ----------------
// factor 64x64 diagonal block in LDS; also compute Winv = L11^{-1}
__global__ __launch_bounds__(256) void chol_diag(float* __restrict__ A, float* __restrict__ Winv, int kstep) {
  int b = blockIdx.x;
  float* Ab = A + (size_t)b * PB + (size_t)(kstep * 64) * CN + kstep * 64;
  __shared__ float Ds[64][65];
  __shared__ float Ws[64][65];
  int tid = threadIdx.x;
  for (int idx = tid; idx < 4096; idx += 256) {
    int j = idx >> 6, l = idx & 63;
    Ds[j][l] = Ab[(size_t)j * CN + l];
    Ws[j][l] = (j == l) ? 1.f : 0.f;
  }
  __syncthreads();
  for (int i = 0; i < 64; ++i) {
    float dii = Ds[i][i];
    float lii = sqrtf(dii);
    float rinv = 1.0f / lii;
    __syncthreads();
    if (tid < 64) {
      if (tid > i) Ds[tid][i] *= rinv;
      else if (tid == i) Ds[i][i] = lii;
    }
    __syncthreads();
    for (int idx = tid; idx < 4096; idx += 256) {
      int j = idx >> 6, l = idx & 63;
      if (l > i && j >= l) Ds[j][l] -= Ds[j][i] * Ds[l][i];
    }
    __syncthreads();
  }
  // Ws = L^{-1} (forward substitution, update form)
  for (int i = 0; i < 64; ++i) {
    if (tid < 64) Ws[i][tid] = Ws[i][tid] / Ds[i][i];
    __syncthreads();
    for (int idx = tid; idx < 4096; idx += 256) {
      int j = idx >> 6, l = idx & 63;
      if (j > i) Ws[j][l] -= Ds[j][i] * Ws[i][l];
    }
    __syncthreads();
  }
  for (int idx = tid; idx < 4096; idx += 256) {
    int j = idx >> 6, l = idx & 63;
    Ab[(size_t)j * CN + l] = Ds[j][l];
    Winv[(size_t)b * 4096 + idx] = Ws[j][l];
  }
}

__global__ __launch_bounds__(256) void transpose_k(const float* __restrict__ L, float* __restrict__ LT) {
  __shared__ float s[64][65];
  int b = blockIdx.z;
  int i0 = blockIdx.y * 64, j0 = blockIdx.x * 64;
  const float* Lb = L + (size_t)b * PB;
  float* Tb = LT + (size_t)b * PB;
  for (int idx = threadIdx.x; idx < 4096; idx += 256) {
    int j = idx >> 6, l = idx & 63;
    s[j][l] = Lb[(size_t)(i0 + j) * CN + j0 + l];
  }
  __syncthreads();
  for (int idx = threadIdx.x; idx < 4096; idx += 256) {
    int j = idx >> 6, l = idx & 63;
    Tb[(size_t)(j0 + j) * CN + i0 + l] = s[l][j];
  }
}

// ---------------- triangular solves: prec = L^{-T} L^{-1} ----------------
// forward: L Y = I. wave handles column c; LDS-shared LT row per step.
__global__ __launch_bounds__(512) void tri_fwd(const float* __restrict__ Lm, const float* __restrict__ LTm,
                                               float* __restrict__ Yt) {
  int b = blockIdx.y;
  int wave = threadIdx.x >> 6, lane = threadIdx.x & 63;
  int c = blockIdx.x * 8 + wave;
  const float* Lb = Lm + (size_t)b * PB;
  const float* LTb = LTm + (size_t)b * PB;
  __shared__ float row[2][CN];
  __shared__ float dg[CN];
  dg[threadIdx.x] = Lb[(size_t)threadIdx.x * CN + threadIdx.x];
  row[0][threadIdx.x] = LTb[threadIdx.x];
  __syncthreads();
  float acc[8] = {0, 0, 0, 0, 0, 0, 0, 0};
  float yv[8];
#pragma unroll
  for (int r = 0; r < 8; ++r) {
    for (int ii = 0; ii < 64; ++ii) {
      int i = r * 64 + ii;
      float nxt = 0.f;
      if (i + 1 < CN) nxt = LTb[(size_t)(i + 1) * CN + threadIdx.x];
      float a = __shfl(acc[r], ii);
      float y = (((i == c) ? 1.0f : 0.0f) - a) / dg[i];
      if (lane == ii) yv[r] = y;
      int cur = i & 1;
#pragma unroll
      for (int rr = 0; rr < 8; ++rr) acc[rr] += row[cur][rr * 64 + lane] * y;
      __syncthreads();
      row[cur ^ 1][threadIdx.x] = nxt;
      __syncthreads();
    }
  }
#pragma unroll
  for (int rr = 0; rr < 8; ++rr)
    Yt[(size_t)b * PB + (size_t)c * CN + rr * 64 + lane] = yv[rr];
}

// backward: L^T X = Y, in place on Yt. wave c; LDS-shared L row per step.
__global__ __launch_bounds__(512) void tri_bwd(const float* __restrict__ Lm, float* __restrict__ Yt) {
  int b = blockIdx.y;
  int wave = threadIdx.x >> 6, lane = threadIdx.x & 63;
  int c = blockIdx.x * 8 + wave;
  const float* Lb = Lm + (size_t)b * PB;
  float* Yrow = Yt + (size_t)b * PB + (size_t)c * CN;
  __shared__ float row[2][CN];
  __shared__ float dg[CN];
  dg[threadIdx.x] = Lb[(size_t)threadIdx.x * CN + threadIdx.x];
  row[(CN - 1) & 1][threadIdx.x] = Lb[(size_t)(CN - 1) * CN + threadIdx.x];
  float yv[8], xv[8];
#pragma unroll
  for (int rr = 0; rr < 8; ++rr) yv[rr] = Yrow[rr * 64 + lane];
  float acc[8] = {0, 0, 0, 0, 0, 0, 0, 0};
  __syncthreads();
#pragma unroll
  for (int r = 7; r >= 0; --r) {
    for (int ii = 63; ii >= 0; --ii) {
      int k = r * 64 + ii;
      float nxt = 0.f;
      if (k > 0) nxt = Lb[(size_t)(k - 1) * CN + threadIdx.x];
      float a = __shfl(acc[r], ii);
      float yk = __shfl(yv[r], ii);
      float xk = (yk - a) / dg[k];
      if (lane == ii) xv[r] = xk;
      int cur = k & 1;
#pragma unroll
      for (int rr = 0; rr < 8; ++rr) acc[rr] += row[cur][rr * 64 + lane] * xk;
      __syncthreads();
      row[cur ^ 1][threadIdx.x] = nxt;
      __syncthreads();
    }
  }
#pragma unroll
  for (int rr = 0; rr < 8; ++rr) Yrow[rr * 64 + lane] = xv[rr];
}

__global__ void sdp_k(const float* __restrict__ prec, float* __restrict__ sdp) {
  int idx = blockIdx.x * 256 + threadIdx.x;
  int b = idx >> 9, i = idx & (CN - 1);
  sdp[idx] = sqrtf(fmaxf(prec[(size_t)b * PB + (size_t)i * (CN + 1)], EPSF));
}

// ---------------- similarity sums over strict upper triangle ----------------
__global__ __launch_bounds__(256) void fuse_sums(const float* __restrict__ covx, const float* __restrict__ covr,
                                                 const float* __restrict__ prec, const float* __restrict__ sdx,
                                                 const float* __restrict__ sdr, const float* __restrict__ sdp,
                                                 float* __restrict__ sums) {
  int b = blockIdx.y;
  int base = blockIdx.x * 2048;
  float pp = 0, ss = 0, cc = 0, ps = 0, pc = 0, sc = 0;
  for (int u = 0; u < 8; ++u) {
    int e = base + u * 256 + threadIdx.x;
    int i = e >> 9, j = e & (CN - 1);
    if (j > i) {
      size_t off = (size_t)b * PB + e;
      float p = covx[off] / (sdx[b * CN + i] * sdx[b * CN + j]);
      float s = covr[off] / (sdr[b * CN + i] * sdr[b * CN + j]);
      float cv = tanhf(-prec[off] / (sdp[b * CN + i] * sdp[b * CN + j]));
      pp += p * p; ss += s * s; cc += cv * cv;
      ps += p * s; pc += p * cv; sc += s * cv;
    }
  }
  __shared__ float red[256];
  float vals[6] = {pp, ss, cc, ps, pc, sc};
#pragma unroll
  for (int v = 0; v < 6; ++v) {
    red[threadIdx.x] = vals[v];
    __syncthreads();
    for (int s2 = 128; s2 > 0; s2 >>= 1) {
      if (threadIdx.x < s2) red[threadIdx.x] += red[threadIdx.x + s2];
      __syncthreads();
    }
    if (threadIdx.x == 0) atomicAdd(&sums[b * 6 + v], red[0]);
    __syncthreads();
  }
}

__global__ void alphas_k(const float* __restrict__ sums, const float* __restrict__ gamma,
                         float* __restrict__ alph) {
  int b = threadIdx.x;
  if (b >= CB) return;
  float sPP = sums[b * 6 + 0], sSS = sums[b * 6 + 1], sCC = sums[b * 6 + 2];
  float sPS = sums[b * 6 + 3], sPC = sums[b * 6 + 4], sSC = sums[b * 6 + 5];
  float numP = 0.5f * (sPS + sPC), numS = 0.5f * (sPS + sSC), numC = 0.5f * (sPC + sSC);
  float noP = 0.5f * sqrtf(sSS + sCC + 2.f * sSC);
  float noS = 0.5f * sqrtf(sPP + sCC + 2.f * sPC);
  float noC = 0.5f * sqrtf(sPP + sSS + 2.f * sPS);
  float dP = fmaxf(sqrtf(sPP), EPSF) * fmaxf(noP, EPSF);
  float dS = fmaxf(sqrtf(sSS), EPSF) * fmaxf(noS, EPSF);
  float dC = fmaxf(sqrtf(sCC), EPSF) * fmaxf(noC, EPSF);
  float g = gamma[0];
  float aP = g * numP / dP, aS = g * numS / dS, aC = g * numC / dC;
  float m = fmaxf(fmaxf(aP, aS), aC);
  float eP = expf(aP - m), eS = expf(aS - m), eC = expf(aC - m);
  float inv = 1.f / (eP + eS + eC);
  alph[b * 3 + 0] = eP * inv;
  alph[b * 3 + 1] = eS * inv;
  alph[b * 3 + 2] = eC * inv;
}

// ---------------- A_fused (symmetrized, unit diag) ----------------
__global__ __launch_bounds__(256) void build_fused(const float* __restrict__ covx, const float* __restrict__ covr,
                                                   const float* __restrict__ prec, const float* __restrict__ sdx,
                                                   const float* __restrict__ sdr, const float* __restrict__ sdp,
                                                   const float* __restrict__ alph, float* __restrict__ Af) {
  int b = blockIdx.y;
  int e = blockIdx.x * 256 + threadIdx.x;   // < PB
  int i = e >> 9, j = e & (CN - 1);
  size_t off = (size_t)b * PB + e;
  float v;
  if (i == j) {
    v = 1.0f;
  } else {
    float p = covx[off] / (sdx[b * CN + i] * sdx[b * CN + j]);
    float s = covr[off] / (sdr[b * CN + i] * sdr[b * CN + j]);
    float c1 = tanhf(-prec[off] / (sdp[b * CN + i] * sdp[b * CN + j]));
    size_t offT = (size_t)b * PB + (size_t)j * CN + i;
    float c2 = tanhf(-prec[offT] / (sdp[b * CN + j] * sdp[b * CN + i]));
    v = alph[b * 3 + 0] * p + alph[b * 3 + 1] * s + alph[b * 3 + 2] * 0.5f * (c1 + c2);
  }
  Af[off] = v;
}

__global__ __launch_bounds__(256) void rowsum_k(const float* __restrict__ Af, float* __restrict__ dinv) {
  int row = blockIdx.x;   // b*CN + i
  const float* r = Af + (size_t)row * CN;
  __shared__ float red[256];
  red[threadIdx.x] = r[threadIdx.x] + r[threadIdx.x + 256];
  __syncthreads();
  for (int s = 128; s > 0; s >>= 1) {
    if (threadIdx.x < s) red[threadIdx.x] += red[threadIdx.x + s];
    __syncthreads();
  }
  if (threadIdx.x == 0) dinv[row] = 1.0f / sqrtf(fmaxf(red[0], EPSF));
}

__global__ __launch_bounds__(256) void norm_adj_k(float* __restrict__ Af, const float* __restrict__ dinv) {
  int b = blockIdx.y;
  int e = blockIdx.x * 256 + threadIdx.x;
  int i = e >> 9, j = e & (CN - 1);
  Af[(size_t)b * PB + e] *= dinv[b * CN + i] * dinv[b * CN + j];
}

// ---------------- X features + LayerNorm ----------------
__global__ __launch_bounds__(256) void xbuild_k(const float* __restrict__ covx, const float* __restrict__ covr,
                                                const float* __restrict__ prec, const float* __restrict__ sdx,
                                                const float* __restrict__ sdr, const float* __restrict__ sdp,
                                                const float* __restrict__ lng, const float* __restrict__ lnb,
                                                float* __restrict__ Xn) {
  int b = blockIdx.y, n = blockIdx.x;
  __shared__ float vals[CIN];
  __shared__ float rs[256], rq[256];
  const float* cvx = covx + (size_t)b * PB + (size_t)n * CN;
  const float* cvr = covr + (size_t)b * PB + (size_t)n * CN;
  const float* prc = prec + (size_t)b * PB + (size_t)n * CN;
  float snx = sdx[b * CN + n], snr = sdr[b * CN + n], snp = sdp[b * CN + n];
  float ls = 0.f, lq = 0.f;
#pragma unroll
  for (int k = 0; k < 6; ++k) {
    int pos = k * 256 + threadIdx.x;
    int part = pos >> 9;
    int j = pos & (CN - 1);
    float v;
    if (part == 0)      v = (j == n) ? 1.0f : cvx[j] / (snx * sdx[b * CN + j]);
    else if (part == 1) v = (j == n) ? 1.0f : cvr[j] / (snr * sdr[b * CN + j]);
    else                v = (j == n) ? tanhf(1.0f) : tanhf(-prc[j] / (snp * sdp[b * CN + j]));
    vals[pos] = v;
    ls += v; lq += v * v;
  }
  rs[threadIdx.x] = ls; rq[threadIdx.x] = lq;
  __syncthreads();
  for (int s = 128; s > 0; s >>= 1) {
    if (threadIdx.x < s) { rs[threadIdx.x] += rs[threadIdx.x + s]; rq[threadIdx.x] += rq[threadIdx.x + s]; }
    __syncthreads();
  }
  float mu = rs[0] * (1.0f / CIN);
  float var = rq[0] * (1.0f / CIN) - mu * mu;
  float rstd = 1.0f / sqrtf(var + 1e-5f);
  float* Xrow = Xn + ((size_t)b * CN + n) * CIN;
#pragma unroll
  for (int k = 0; k < 6; ++k) {
    int pos = k * 256 + threadIdx.x;
    Xrow[pos] = (vals[pos] - mu) * rstd * lng[pos] + lnb[pos];
  }
}

// ---------------- head ----------------
__global__ __launch_bounds__(256) void gmean_k(const float* __restrict__ H, float* __restrict__ gm) {
  int b = blockIdx.y;
  int d = blockIdx.x * 256 + threadIdx.x;
  const float* Hb = H + (size_t)b * CN * CD + d;
  float s = 0.f;
  for (int n = 0; n < CN; ++n) s += Hb[(size_t)n * CD];
  gm[b * CD + d] = s * (1.0f / CN);
}

__global__ __launch_bounds__(256) void final_k(const float* __restrict__ gm, const float* __restrict__ Wc,
                                               const float* __restrict__ bc, float* __restrict__ out) {
  int b = blockIdx.x;
  __shared__ float red[256];
  float s = gm[b * CD + threadIdx.x] * Wc[threadIdx.x] +
            gm[b * CD + 256 + threadIdx.x] * Wc[256 + threadIdx.x];
  red[threadIdx.x] = s;
  __syncthreads();
  for (int k = 128; k > 0; k >>= 1) {
    if (threadIdx.x < k) red[threadIdx.x] += red[threadIdx.x + k];
    __syncthreads();
  }
  if (threadIdx.x == 0) {
    float z = red[0] + bc[0];
    out[b] = 1.0f / (1.0f + expf(-z));
  }
}

// ---------------- launcher ----------------
extern "C" void kernel_launch(void* const* d_in, const int* in_sizes, int n_in,
                              void* d_out, int out_size, void* d_ws, size_t ws_size,
                              hipStream_t stream) {
  const float* x    = (const float*)d_in[0];
  const float* gam  = (const float*)d_in[1];
  const float* lng  = (const float*)d_in[2];
  const float* lnb  = (const float*)d_in[3];
  const float* W0   = (const float*)d_in[4];
  const float* b0   = (const float*)d_in[5];
  const float* W1   = (const float*)d_in[6];
  const float* b1   = (const float*)d_in[7];
  const float* W2   = (const float*)d_in[8];
  const float* b2   = (const float*)d_in[9];
  const float* Wc   = (const float*)d_in[10];
  const float* bc   = (const float*)d_in[11];
  float* out = (float*)d_out;
  float* ws = (float*)d_ws;

  // workspace layout (floats). region A [0, 16777216) = xm+rm, later Xn+Af.
  float* xm   = ws;
  float* rm   = ws + SBTN;
  float* Xn   = ws;                      // reuse (xm/rm dead)
  float* Af   = ws + 12582912;           // 16*512*1536 .. 16777216
  float* covx = ws + 16777216;
  float* covr = covx + SBNN;
  float* Lm   = covx + 2 * SBNN;
  float* LTm  = covx + 3 * SBNN;
  float* prY  = covx + 4 * SBNN;         // Yt, then prec in-place
  float* Winv = covx + 5 * SBNN;         // 16*4096
  float* sdx  = Winv + 65536;
  float* sdr  = sdx + 8192;
  float* sdp  = sdr + 8192;
  float* dinv = sdp + 8192;
  float* gm   = dinv + 8192;
  float* ms   = gm + 8192;
  float* sums = ms + 8192;
  // GCN buffer reuse (all dead by then):
  float* G  = Lm;
  float* Ha = LTm;
  float* Hb = prY;
  float* alph = sums + 96;

  const float covscale = (float)(1.0 / 1023.00000001);
  const long long sTN = (long long)CT * CN;
  const long long sPB = (long long)PB;
  const long long sND = (long long)CN * CD;

  // means + centering + ranks
  zero_k<<<(8288 + 255) / 256, 256, 0, stream>>>(ms, 8288);   // ms + sums
  colmean_k<<<dim3(2, CB, 4), 256, 0, stream>>>(x, ms);
  center_k<<<(int)(SBTN / 256), 256, 0, stream>>>(x, ms, xm);
  ranks_k<<<dim3(CN / 4, CB), 256, 0, stream>>>(x, rm);

  // covariances (syrk, K=1024)
  gemm_k<true, false, false, false><<<dim3(8, 8, CB), 256, 0, stream>>>(
      xm, xm, nullptr, covx, CN, CN, CT, CN, CN, CN, sTN, sTN, sPB, covscale);
  gemm_k<true, false, false, false><<<dim3(8, 8, CB), 256, 0, stream>>>(
      rm, rm, nullptr, covr, CN, CN, CT, CN, CN, CN, sTN, sTN, sPB, covscale);
  sds_k<<<32, 256, 0, stream>>>(covx, covr, sdx, sdr);
  ridge_k<<<(int)(SBNN / 256), 256, 0, stream>>>(covx, Lm);

  // blocked Cholesky (NB=64)
  for (int k = 0; k < 8; ++k) {
    chol_diag<<<CB, 256, 0, stream>>>(Lm, Winv, k);
    int Mt = CN - 64 * (k + 1);
    if (Mt > 0) {
      float* Apan = Lm + (size_t)(k + 1) * 64 * CN + k * 64;
      float* Atrl = Lm + (size_t)(k + 1) * 64 * CN + (k + 1) * 64;
      // panel: P <- P * Winv^T
      gemm_k<false, true, false, false><<<dim3(1, Mt / 64, CB), 256, 0, stream>>>(
          Apan, Winv, nullptr, Apan, Mt, 64, 64, CN, 64, CN, sPB, 4096LL, sPB, 1.0f);
      // trailing: A22 -= P * P^T
      gemm_k<false, true, true, false><<<dim3(Mt / 64, Mt / 64, CB), 256, 0, stream>>>(
          Apan, Apan, nullptr, Atrl, Mt, Mt, 64, CN, CN, CN, sPB, sPB, sPB, -1.0f);
    }
  }
  transpose_k<<<dim3(8, 8, CB), 256, 0, stream>>>(Lm, LTm);
  tri_fwd<<<dim3(64, CB), 512, 0, stream>>>(Lm, LTm, prY);
  tri_bwd<<<dim3(64, CB), 512, 0, stream>>>(Lm, prY);
  sdp_k<<<32, 256, 0, stream>>>(prY, sdp);

  // similarity -> alphas -> fused adjacency -> normalize
  fuse_sums<<<dim3(128, CB), 256, 0, stream>>>(covx, covr, prY, sdx, sdr, sdp, sums);
  alphas_k<<<1, 64, 0, stream>>>(sums, gam, alph);
  build_fused<<<dim3(1024, CB), 256, 0, stream>>>(covx, covr, prY, sdx, sdr, sdp, alph, Af);
  rowsum_k<<<CB * CN, 256, 0, stream>>>(Af, dinv);
  norm_adj_k<<<dim3(1024, CB), 256, 0, stream>>>(Af, dinv);

  // features + layernorm
  xbuild_k<<<dim3(CN, CB), 256, 0, stream>>>(covx, covr, prY, sdx, sdr, sdp, lng, lnb, Xn);

  // GCN: H = relu(Anorm @ (H @ W + b)) x3
  gemm_k<false, false, false, false><<<dim3(8, 128, 1), 256, 0, stream>>>(
      Xn, W0, b0, G, CB * CN, CD, CIN, CIN, CD, CD, 0, 0, 0, 1.0f);
  gemm_k<false, false, false, true><<<dim3(8, 8, CB), 256, 0, stream>>>(
      Af, G, nullptr, Ha, CN, CD, CN, CN, CD, CD, sPB, sND, sND, 1.0f);
  gemm_k<false, false, false, false><<<dim3(8, 128, 1), 256, 0, stream>>>(
      Ha, W1, b1, G, CB * CN, CD, CD, CD, CD, CD, 0, 0, 0, 1.0f);
  gemm_k<false, false, false, true><<<dim3(8, 8, CB), 256, 0, stream>>>(
      Af, G, nullptr, Hb, CN, CD, CN, CN, CD, CD, sPB, sND, sND, 1.0f);
  gemm_k<false, false, false, false><<<dim3(8, 128, 1), 256, 0, stream>>>(
      Hb, W2, b2, G, CB * CN, CD, CD, CD, CD, CD, 0, 0, 0, 1.0f);
  gemm_k<false, false, false, true><<<dim3(8, 8, CB), 256, 0, stream>>>(
      Af, G, nullptr, Ha, CN, CD, CN, CN, CD, CD, sPB, sND, sND, 1.0f);

  gmean_k<<<dim3(2, CB), 256, 0, stream>>>(Ha, gm);
  final_k<<<CB, 256, 0, stream>>>(gm, Wc, bc, out);
}

// Round 2
// 3264.561 us; speedup vs baseline: 1.1077x; 1.1077x over previous
//
#include <hip/hip_runtime.h>
#include <math.h>

#define EPSF 1e-8f

constexpr int CB = 16;      // batch
constexpr int CT = 1024;    // time
constexpr int CN = 512;     // nodes
constexpr int CD = 512;     // hidden
constexpr int CIN = 1536;   // 3*N
constexpr int PB = CN * CN;                 // 262144 per-batch matrix elems
constexpr size_t SBTN = (size_t)CB * CT * CN;   // 8,388,608
constexpr size_t SBNN = (size_t)CB * PB;        // 4,194,304

// ---------------- utility ----------------
__global__ void zero_k(float* p, int n) {
  int i = blockIdx.x * 256 + threadIdx.x;
  if (i < n) p[i] = 0.f;
}

// ---------------- column means + centering ----------------
__global__ __launch_bounds__(256) void colmean_k(const float* __restrict__ x, float* __restrict__ ms) {
  int b = blockIdx.y;
  int n = blockIdx.x * 256 + threadIdx.x;
  int t0 = blockIdx.z * 256;
  const float* xb = x + (size_t)b * CT * CN + (size_t)t0 * CN + n;
  float s = 0.f;
  for (int t = 0; t < 256; ++t) s += xb[(size_t)t * CN];
  atomicAdd(&ms[b * CN + n], s);
}

__global__ __launch_bounds__(256) void center_k(const float* __restrict__ x, const float* __restrict__ ms,
                                                float* __restrict__ xm) {
  size_t e = (size_t)blockIdx.x * 256 + threadIdx.x;
  int b = (int)(e >> 19);          // T*N = 2^19
  int n = (int)(e & (CN - 1));
  xm[e] = x[e] - ms[b * CN + n] * (1.0f / CT);
}

// ---------------- Spearman ranks via in-LDS bitonic sort ----------------
// key = sortable_u32(x), payload = original index t; ties broken on index ->
// exact stable argsort-of-argsort semantics. Rank written pre-centered.
__global__ __launch_bounds__(256) void ranks_k(const float* __restrict__ x, float* __restrict__ rm) {
  int b = blockIdx.y;
  int n0 = blockIdx.x * 4;
  __shared__ unsigned int key[4][1032];   // pad 1032: c-stride hits distinct banks
  __shared__ unsigned int idxs[4][1032];
  const float* xb = x + (size_t)b * CT * CN + n0;
  for (int t = threadIdx.x; t < 1024; t += 256) {
    float4 v = *(const float4*)&xb[(size_t)t * CN];
    float vv[4] = {v.x, v.y, v.z, v.w};
#pragma unroll
    for (int c = 0; c < 4; ++c) {
      unsigned int u = __float_as_uint(vv[c]);
      u = (u & 0x80000000u) ? ~u : (u | 0x80000000u);
      key[c][t] = u;
      idxs[c][t] = t;
    }
  }
  __syncthreads();
  const int c = threadIdx.x >> 6;       // one wave per column
  const int lane = threadIdx.x & 63;
  unsigned int* K = key[c];
  unsigned int* I = idxs[c];
  for (int k = 2; k <= 1024; k <<= 1) {
    for (int j = k >> 1; j >= 1; j >>= 1) {
#pragma unroll
      for (int m = 0; m < 8; ++m) {
        int t = m * 64 + lane;
        int i = 2 * t - (t & (j - 1));   // enumerates all i with (i & j)==0
        int l = i + j;
        unsigned int k1 = K[i], k2 = K[l];
        unsigned int i1 = I[i], i2 = I[l];
        bool gt = (k1 > k2) || (k1 == k2 && i1 > i2);
        bool up = ((i & k) == 0);
        if (gt == up) {
          K[i] = k2; K[l] = k1;
          I[i] = i2; I[l] = i1;
        }
      }
      __syncthreads();
    }
  }
  // invert permutation in LDS: element at sorted position p has rank p+1
#pragma unroll
  for (int m = 0; m < 16; ++m) {
    int p = m * 64 + lane;
    K[I[p]] = __float_as_uint((float)(p + 1) - 512.5f);
  }
  __syncthreads();
  float* rmb = rm + (size_t)b * CT * CN + n0;
  for (int t = threadIdx.x; t < 1024; t += 256) {
    float4 o;
    o.x = __uint_as_float(key[0][t]);
    o.y = __uint_as_float(key[1][t]);
    o.z = __uint_as_float(key[2][t]);
    o.w = __uint_as_float(key[3][t]);
    *(float4*)&rmb[(size_t)t * CN] = o;
  }
}

// ---------------- generic fp32 tiled GEMM ----------------
// C = alpha * op(A) * op(B) [+ C if ACC] [+ bias] [relu]
// TA: A stored (K x M) row-major (lda = row stride). else (M x K).
// TB: B stored (N x K) row-major (ldb = row stride). else (K x N).
template<bool TA, bool TB, bool ACC, bool RELU>
__global__ __launch_bounds__(256) void gemm_k(
    const float* __restrict__ A, const float* __restrict__ B,
    const float* __restrict__ bias, float* __restrict__ C,
    int M, int Nc, int K, int lda, int ldb, int ldc,
    long long sA, long long sB, long long sC, float alpha) {
  __shared__ float As[16][68];
  __shared__ float Bs[16][68];
  const int bz = blockIdx.z;
  A += (size_t)bz * sA;
  B += (size_t)bz * sB;
  C += (size_t)bz * sC;
  const int n0 = blockIdx.x * 64;
  const int m0 = blockIdx.y * 64;
  const int tid = threadIdx.x;
  const int tn = (tid & 15) * 4;
  const int tm = (tid >> 4) * 4;
  float acc[4][4];
#pragma unroll
  for (int i = 0; i < 4; ++i)
#pragma unroll
    for (int j = 0; j < 4; ++j) acc[i][j] = 0.f;

  for (int k0 = 0; k0 < K; k0 += 16) {
    if (TA) {
      const int lk = tid >> 4;
      const int lm = (tid & 15) * 4;
      const float4 v = *(const float4*)&A[(size_t)(k0 + lk) * lda + m0 + lm];
      *(float4*)&As[lk][lm] = v;
    } else {
      const int lm = tid >> 2;
      const int lk = (tid & 3) * 4;
      const float4 v = *(const float4*)&A[(size_t)(m0 + lm) * lda + k0 + lk];
      As[lk + 0][lm] = v.x; As[lk + 1][lm] = v.y; As[lk + 2][lm] = v.z; As[lk + 3][lm] = v.w;
    }
    if (TB) {
      const int ln = tid >> 2;
      const int lk = (tid & 3) * 4;
      const float4 v = *(const float4*)&B[(size_t)(n0 + ln) * ldb + k0 + lk];
      Bs[lk + 0][ln] = v.x; Bs[lk + 1][ln] = v.y; Bs[lk + 2][ln] = v.z; Bs[lk + 3][ln] = v.w;
    } else {
      const int lk = tid >> 4;
      const int ln = (tid & 15) * 4;
      const float4 v = *(const float4*)&B[(size_t)(k0 + lk) * ldb + n0 + ln];
      *(float4*)&Bs[lk][ln] = v;
    }
    __syncthreads();
#pragma unroll
    for (int kk = 0; kk < 16; ++kk) {
      const float4 a4 = *(const float4*)&As[kk][tm];
      const float4 b4 = *(const float4*)&Bs[kk][tn];
      const float av[4] = {a4.x, a4.y, a4.z, a4.w};
      const float bv[4] = {b4.x, b4.y, b4.z, b4.w};
#pragma unroll
      for (int i = 0; i < 4; ++i)
#pragma unroll
        for (int j = 0; j < 4; ++j) acc[i][j] = fmaf(av[i], bv[j], acc[i][j]);
    }
    __syncthreads();
  }
  float4 bb = make_float4(0.f, 0.f, 0.f, 0.f);
  if (bias) bb = *(const float4*)&bias[n0 + tn];
#pragma unroll
  for (int i = 0; i < 4; ++i) {
    size_t off = (size_t)(m0 + tm + i) * ldc + (n0 + tn);
    float4 v;
    v.x = alpha * acc[i][0] + bb.x;
    v.y = alpha * acc[i][1] + bb.y;
    v.z = alpha * acc[i][2] + bb.z;
    v.w = alpha * acc[i][3] + bb.w;
    if (ACC) {
      const float4 c0 = *(const float4*)&C[off];
      v.x += c0.x; v.y += c0.y; v.z += c0.z; v.w += c0.w;
    }
    if (RELU) {
      v.x = fmaxf(v.x, 0.f); v.y = fmaxf(v.y, 0.f);
      v.z = fmaxf(v.z, 0.f); v.w = fmaxf(v.w, 0.f);
    }
    *(float4*)&C[off] = v;
  }
}

// ---------------- std vectors ----------------
__global__ void sds_k(const float* __restrict__ covx, const float* __restrict__ covr,
                      float* __restrict__ sdx, float* __restrict__ sdr) {
  int idx = blockIdx.x * 256 + threadIdx.x;     // < CB*CN
  int b = idx >> 9, i = idx & (CN - 1);
  size_t off = (size_t)b * PB + (size_t)i * (CN + 1);
  sdx[idx] = sqrtf(fmaxf(covx[off], EPSF));
  sdr[idx] = sqrtf(fmaxf(covr[off], EPSF));
}

__global__ void ridge_k(const float* __restrict__ covx, float* __restrict__ A) {
  size_t e = (size_t)blockIdx.x * 256 + threadIdx.x;  // < SBNN
  int ij = (int)(e & (PB - 1));
  int i = ij >> 9, j = ij & (CN - 1);
  A[e] = covx[e] + ((i == j) ? 0.001f : 0.0f);
}

// ---------------- blocked Cholesky pieces ----------------
// factor 64x64 diagonal block in LDS; also compute Winv = L11^{-1}
__global__ __launch_bounds__(256) void chol_diag(float* __restrict__ A, float* __restrict__ Winv, int kstep) {
  int b = blockIdx.x;
  float* Ab = A + (size_t)b * PB + (size_t)(kstep * 64) * CN + kstep * 64;
  __shared__ float Ds[64][65];
  __shared__ float Ws[64][65];
  int tid = threadIdx.x;
  for (int idx = tid; idx < 4096; idx += 256) {
    int j = idx >> 6, l = idx & 63;
    Ds[j][l] = Ab[(size_t)j * CN + l];
    Ws[j][l] = (j == l) ? 1.f : 0.f;
  }
  __syncthreads();
  for (int i = 0; i < 64; ++i) {
    float dii = Ds[i][i];
    float lii = sqrtf(dii);
    float rinv = 1.0f / lii;
    __syncthreads();
    if (tid < 64) {
      if (tid > i) Ds[tid][i] *= rinv;
      else if (tid == i) Ds[i][i] = lii;
    }
    __syncthreads();
    for (int idx = tid; idx < 4096; idx += 256) {
      int j = idx >> 6, l = idx & 63;
      if (l > i && j >= l) Ds[j][l] -= Ds[j][i] * Ds[l][i];
    }
    __syncthreads();
  }
  // Ws = L^{-1} (forward substitution, update form)
  for (int i = 0; i < 64; ++i) {
    if (tid < 64) Ws[i][tid] = Ws[i][tid] / Ds[i][i];
    __syncthreads();
    for (int idx = tid; idx < 4096; idx += 256) {
      int j = idx >> 6, l = idx & 63;
      if (j > i) Ws[j][l] -= Ds[j][i] * Ws[i][l];
    }
    __syncthreads();
  }
  for (int idx = tid; idx < 4096; idx += 256) {
    int j = idx >> 6, l = idx & 63;
    Ab[(size_t)j * CN + l] = Ds[j][l];
    Winv[(size_t)b * 4096 + idx] = Ws[j][l];
  }
}

__global__ __launch_bounds__(256) void transpose_k(const float* __restrict__ L, float* __restrict__ LT) {
  __shared__ float s[64][65];
  int b = blockIdx.z;
  int i0 = blockIdx.y * 64, j0 = blockIdx.x * 64;
  const float* Lb = L + (size_t)b * PB;
  float* Tb = LT + (size_t)b * PB;
  for (int idx = threadIdx.x; idx < 4096; idx += 256) {
    int j = idx >> 6, l = idx & 63;
    s[j][l] = Lb[(size_t)(i0 + j) * CN + j0 + l];
  }
  __syncthreads();
  for (int idx = threadIdx.x; idx < 4096; idx += 256) {
    int j = idx >> 6, l = idx & 63;
    Tb[(size_t)(j0 + j) * CN + i0 + l] = s[l][j];
  }
}

// ---------------- triangular solves: prec = L^{-T} L^{-1} ----------------
// forward: L Y = I. wave handles column c; LDS-shared LT row per step.
__global__ __launch_bounds__(512) void tri_fwd(const float* __restrict__ Lm, const float* __restrict__ LTm,
                                               float* __restrict__ Yt) {
  int b = blockIdx.y;
  int wave = threadIdx.x >> 6, lane = threadIdx.x & 63;
  int c = blockIdx.x * 8 + wave;
  const float* Lb = Lm + (size_t)b * PB;
  const float* LTb = LTm + (size_t)b * PB;
  __shared__ float row[2][CN];
  __shared__ float dg[CN];
  dg[threadIdx.x] = Lb[(size_t)threadIdx.x * CN + threadIdx.x];
  row[0][threadIdx.x] = LTb[threadIdx.x];
  __syncthreads();
  float acc[8] = {0, 0, 0, 0, 0, 0, 0, 0};
  float yv[8];
#pragma unroll
  for (int r = 0; r < 8; ++r) {
    for (int ii = 0; ii < 64; ++ii) {
      int i = r * 64 + ii;
      float nxt = 0.f;
      if (i + 1 < CN) nxt = LTb[(size_t)(i + 1) * CN + threadIdx.x];
      float a = __shfl(acc[r], ii);
      float y = (((i == c) ? 1.0f : 0.0f) - a) / dg[i];
      if (lane == ii) yv[r] = y;
      int cur = i & 1;
#pragma unroll
      for (int rr = 0; rr < 8; ++rr) acc[rr] += row[cur][rr * 64 + lane] * y;
      __syncthreads();
      row[cur ^ 1][threadIdx.x] = nxt;
      __syncthreads();
    }
  }
#pragma unroll
  for (int rr = 0; rr < 8; ++rr)
    Yt[(size_t)b * PB + (size_t)c * CN + rr * 64 + lane] = yv[rr];
}

// backward: L^T X = Y, in place on Yt. wave c; LDS-shared L row per step.
__global__ __launch_bounds__(512) void tri_bwd(const float* __restrict__ Lm, float* __restrict__ Yt) {
  int b = blockIdx.y;
  int wave = threadIdx.x >> 6, lane = threadIdx.x & 63;
  int c = blockIdx.x * 8 + wave;
  const float* Lb = Lm + (size_t)b * PB;
  float* Yrow = Yt + (size_t)b * PB + (size_t)c * CN;
  __shared__ float row[2][CN];
  __shared__ float dg[CN];
  dg[threadIdx.x] = Lb[(size_t)threadIdx.x * CN + threadIdx.x];
  row[(CN - 1) & 1][threadIdx.x] = Lb[(size_t)(CN - 1) * CN + threadIdx.x];
  float yv[8], xv[8];
#pragma unroll
  for (int rr = 0; rr < 8; ++rr) yv[rr] = Yrow[rr * 64 + lane];
  float acc[8] = {0, 0, 0, 0, 0, 0, 0, 0};
  __syncthreads();
#pragma unroll
  for (int r = 7; r >= 0; --r) {
    for (int ii = 63; ii >= 0; --ii) {
      int k = r * 64 + ii;
      float nxt = 0.f;
      if (k > 0) nxt = Lb[(size_t)(k - 1) * CN + threadIdx.x];
      float a = __shfl(acc[r], ii);
      float yk = __shfl(yv[r], ii);
      float xk = (yk - a) / dg[k];
      if (lane == ii) xv[r] = xk;
      int cur = k & 1;
#pragma unroll
      for (int rr = 0; rr < 8; ++rr) acc[rr] += row[cur][rr * 64 + lane] * xk;
      __syncthreads();
      row[cur ^ 1][threadIdx.x] = nxt;
      __syncthreads();
    }
  }
#pragma unroll
  for (int rr = 0; rr < 8; ++rr) Yrow[rr * 64 + lane] = xv[rr];
}

__global__ void sdp_k(const float* __restrict__ prec, float* __restrict__ sdp) {
  int idx = blockIdx.x * 256 + threadIdx.x;
  int b = idx >> 9, i = idx & (CN - 1);
  sdp[idx] = sqrtf(fmaxf(prec[(size_t)b * PB + (size_t)i * (CN + 1)], EPSF));
}

// ---------------- similarity sums over strict upper triangle ----------------
__global__ __launch_bounds__(256) void fuse_sums(const float* __restrict__ covx, const float* __restrict__ covr,
                                                 const float* __restrict__ prec, const float* __restrict__ sdx,
                                                 const float* __restrict__ sdr, const float* __restrict__ sdp,
                                                 float* __restrict__ sums) {
  int b = blockIdx.y;
  int base = blockIdx.x * 2048;
  float pp = 0, ss = 0, cc = 0, ps = 0, pc = 0, sc = 0;
  for (int u = 0; u < 8; ++u) {
    int e = base + u * 256 + threadIdx.x;
    int i = e >> 9, j = e & (CN - 1);
    if (j > i) {
      size_t off = (size_t)b * PB + e;
      float p = covx[off] / (sdx[b * CN + i] * sdx[b * CN + j]);
      float s = covr[off] / (sdr[b * CN + i] * sdr[b * CN + j]);
      float cv = tanhf(-prec[off] / (sdp[b * CN + i] * sdp[b * CN + j]));
      pp += p * p; ss += s * s; cc += cv * cv;
      ps += p * s; pc += p * cv; sc += s * cv;
    }
  }
  __shared__ float red[256];
  float vals[6] = {pp, ss, cc, ps, pc, sc};
#pragma unroll
  for (int v = 0; v < 6; ++v) {
    red[threadIdx.x] = vals[v];
    __syncthreads();
    for (int s2 = 128; s2 > 0; s2 >>= 1) {
      if (threadIdx.x < s2) red[threadIdx.x] += red[threadIdx.x + s2];
      __syncthreads();
    }
    if (threadIdx.x == 0) atomicAdd(&sums[b * 6 + v], red[0]);
    __syncthreads();
  }
}

__global__ void alphas_k(const float* __restrict__ sums, const float* __restrict__ gamma,
                         float* __restrict__ alph) {
  int b = threadIdx.x;
  if (b >= CB) return;
  float sPP = sums[b * 6 + 0], sSS = sums[b * 6 + 1], sCC = sums[b * 6 + 2];
  float sPS = sums[b * 6 + 3], sPC = sums[b * 6 + 4], sSC = sums[b * 6 + 5];
  float numP = 0.5f * (sPS + sPC), numS = 0.5f * (sPS + sSC), numC = 0.5f * (sPC + sSC);
  float noP = 0.5f * sqrtf(sSS + sCC + 2.f * sSC);
  float noS = 0.5f * sqrtf(sPP + sCC + 2.f * sPC);
  float noC = 0.5f * sqrtf(sPP + sSS + 2.f * sPS);
  float dP = fmaxf(sqrtf(sPP), EPSF) * fmaxf(noP, EPSF);
  float dS = fmaxf(sqrtf(sSS), EPSF) * fmaxf(noS, EPSF);
  float dC = fmaxf(sqrtf(sCC), EPSF) * fmaxf(noC, EPSF);
  float g = gamma[0];
  float aP = g * numP / dP, aS = g * numS / dS, aC = g * numC / dC;
  float m = fmaxf(fmaxf(aP, aS), aC);
  float eP = expf(aP - m), eS = expf(aS - m), eC = expf(aC - m);
  float inv = 1.f / (eP + eS + eC);
  alph[b * 3 + 0] = eP * inv;
  alph[b * 3 + 1] = eS * inv;
  alph[b * 3 + 2] = eC * inv;
}

// ---------------- A_fused (symmetrized, unit diag) ----------------
__global__ __launch_bounds__(256) void build_fused(const float* __restrict__ covx, const float* __restrict__ covr,
                                                   const float* __restrict__ prec, const float* __restrict__ sdx,
                                                   const float* __restrict__ sdr, const float* __restrict__ sdp,
                                                   const float* __restrict__ alph, float* __restrict__ Af) {
  int b = blockIdx.y;
  int e = blockIdx.x * 256 + threadIdx.x;   // < PB
  int i = e >> 9, j = e & (CN - 1);
  size_t off = (size_t)b * PB + e;
  float v;
  if (i == j) {
    v = 1.0f;
  } else {
    float p = covx[off] / (sdx[b * CN + i] * sdx[b * CN + j]);
    float s = covr[off] / (sdr[b * CN + i] * sdr[b * CN + j]);
    float c1 = tanhf(-prec[off] / (sdp[b * CN + i] * sdp[b * CN + j]));
    size_t offT = (size_t)b * PB + (size_t)j * CN + i;
    float c2 = tanhf(-prec[offT] / (sdp[b * CN + j] * sdp[b * CN + i]));
    v = alph[b * 3 + 0] * p + alph[b * 3 + 1] * s + alph[b * 3 + 2] * 0.5f * (c1 + c2);
  }
  Af[off] = v;
}

__global__ __launch_bounds__(256) void rowsum_k(const float* __restrict__ Af, float* __restrict__ dinv) {
  int row = blockIdx.x;   // b*CN + i
  const float* r = Af + (size_t)row * CN;
  __shared__ float red[256];
  red[threadIdx.x] = r[threadIdx.x] + r[threadIdx.x + 256];
  __syncthreads();
  for (int s = 128; s > 0; s >>= 1) {
    if (threadIdx.x < s) red[threadIdx.x] += red[threadIdx.x + s];
    __syncthreads();
  }
  if (threadIdx.x == 0) dinv[row] = 1.0f / sqrtf(fmaxf(red[0], EPSF));
}

__global__ __launch_bounds__(256) void norm_adj_k(float* __restrict__ Af, const float* __restrict__ dinv) {
  int b = blockIdx.y;
  int e = blockIdx.x * 256 + threadIdx.x;
  int i = e >> 9, j = e & (CN - 1);
  Af[(size_t)b * PB + e] *= dinv[b * CN + i] * dinv[b * CN + j];
}

// ---------------- X features + LayerNorm ----------------
__global__ __launch_bounds__(256) void xbuild_k(const float* __restrict__ covx, const float* __restrict__ covr,
                                                const float* __restrict__ prec, const float* __restrict__ sdx,
                                                const float* __restrict__ sdr, const float* __restrict__ sdp,
                                                const float* __restrict__ lng, const float* __restrict__ lnb,
                                                float* __restrict__ Xn) {
  int b = blockIdx.y, n = blockIdx.x;
  __shared__ float vals[CIN];
  __shared__ float rs[256], rq[256];
  const float* cvx = covx + (size_t)b * PB + (size_t)n * CN;
  const float* cvr = covr + (size_t)b * PB + (size_t)n * CN;
  const float* prc = prec + (size_t)b * PB + (size_t)n * CN;
  float snx = sdx[b * CN + n], snr = sdr[b * CN + n], snp = sdp[b * CN + n];
  float ls = 0.f, lq = 0.f;
#pragma unroll
  for (int k = 0; k < 6; ++k) {
    int pos = k * 256 + threadIdx.x;
    int part = pos >> 9;
    int j = pos & (CN - 1);
    float v;
    if (part == 0)      v = (j == n) ? 1.0f : cvx[j] / (snx * sdx[b * CN + j]);
    else if (part == 1) v = (j == n) ? 1.0f : cvr[j] / (snr * sdr[b * CN + j]);
    else                v = (j == n) ? tanhf(1.0f) : tanhf(-prc[j] / (snp * sdp[b * CN + j]));
    vals[pos] = v;
    ls += v; lq += v * v;
  }
  rs[threadIdx.x] = ls; rq[threadIdx.x] = lq;
  __syncthreads();
  for (int s = 128; s > 0; s >>= 1) {
    if (threadIdx.x < s) { rs[threadIdx.x] += rs[threadIdx.x + s]; rq[threadIdx.x] += rq[threadIdx.x + s]; }
    __syncthreads();
  }
  float mu = rs[0] * (1.0f / CIN);
  float var = rq[0] * (1.0f / CIN) - mu * mu;
  float rstd = 1.0f / sqrtf(var + 1e-5f);
  float* Xrow = Xn + ((size_t)b * CN + n) * CIN;
#pragma unroll
  for (int k = 0; k < 6; ++k) {
    int pos = k * 256 + threadIdx.x;
    Xrow[pos] = (vals[pos] - mu) * rstd * lng[pos] + lnb[pos];
  }
}

// ---------------- head ----------------
__global__ __launch_bounds__(256) void gmean_k(const float* __restrict__ H, float* __restrict__ gm) {
  int b = blockIdx.y;
  int d = blockIdx.x * 256 + threadIdx.x;
  const float* Hb = H + (size_t)b * CN * CD + d;
  float s = 0.f;
  for (int n = 0; n < CN; ++n) s += Hb[(size_t)n * CD];
  gm[b * CD + d] = s * (1.0f / CN);
}

__global__ __launch_bounds__(256) void final_k(const float* __restrict__ gm, const float* __restrict__ Wc,
                                               const float* __restrict__ bc, float* __restrict__ out) {
  int b = blockIdx.x;
  __shared__ float red[256];
  float s = gm[b * CD + threadIdx.x] * Wc[threadIdx.x] +
            gm[b * CD + 256 + threadIdx.x] * Wc[256 + threadIdx.x];
  red[threadIdx.x] = s;
  __syncthreads();
  for (int k = 128; k > 0; k >>= 1) {
    if (threadIdx.x < k) red[threadIdx.x] += red[threadIdx.x + k];
    __syncthreads();
  }
  if (threadIdx.x == 0) {
    float z = red[0] + bc[0];
    out[b] = 1.0f / (1.0f + expf(-z));
  }
}

// ---------------- launcher ----------------
extern "C" void kernel_launch(void* const* d_in, const int* in_sizes, int n_in,
                              void* d_out, int out_size, void* d_ws, size_t ws_size,
                              hipStream_t stream) {
  const float* x    = (const float*)d_in[0];
  const float* gam  = (const float*)d_in[1];
  const float* lng  = (const float*)d_in[2];
  const float* lnb  = (const float*)d_in[3];
  const float* W0   = (const float*)d_in[4];
  const float* b0   = (const float*)d_in[5];
  const float* W1   = (const float*)d_in[6];
  const float* b1   = (const float*)d_in[7];
  const float* W2   = (const float*)d_in[8];
  const float* b2   = (const float*)d_in[9];
  const float* Wc   = (const float*)d_in[10];
  const float* bc   = (const float*)d_in[11];
  float* out = (float*)d_out;
  float* ws = (float*)d_ws;

  // workspace layout (floats). region A [0, 16777216) = xm+rm, later Xn+Af.
  float* xm   = ws;
  float* rm   = ws + SBTN;
  float* Xn   = ws;                      // reuse (xm/rm dead)
  float* Af   = ws + 12582912;           // 16*512*1536 .. 16777216
  float* covx = ws + 16777216;
  float* covr = covx + SBNN;
  float* Lm   = covx + 2 * SBNN;
  float* LTm  = covx + 3 * SBNN;
  float* prY  = covx + 4 * SBNN;         // Yt, then prec in-place
  float* Winv = covx + 5 * SBNN;         // 16*4096
  float* sdx  = Winv + 65536;
  float* sdr  = sdx + 8192;
  float* sdp  = sdr + 8192;
  float* dinv = sdp + 8192;
  float* gm   = dinv + 8192;
  float* ms   = gm + 8192;
  float* sums = ms + 8192;
  // GCN buffer reuse (all dead by then):
  float* G  = Lm;
  float* Ha = LTm;
  float* Hb = prY;
  float* alph = sums + 96;

  const float covscale = (float)(1.0 / 1023.00000001);
  const long long sTN = (long long)CT * CN;
  const long long sPB = (long long)PB;
  const long long sND = (long long)CN * CD;

  // means + centering + ranks
  zero_k<<<(8288 + 255) / 256, 256, 0, stream>>>(ms, 8288);   // ms + sums
  colmean_k<<<dim3(2, CB, 4), 256, 0, stream>>>(x, ms);
  center_k<<<(int)(SBTN / 256), 256, 0, stream>>>(x, ms, xm);
  ranks_k<<<dim3(CN / 4, CB), 256, 0, stream>>>(x, rm);

  // covariances (syrk, K=1024)
  gemm_k<true, false, false, false><<<dim3(8, 8, CB), 256, 0, stream>>>(
      xm, xm, nullptr, covx, CN, CN, CT, CN, CN, CN, sTN, sTN, sPB, covscale);
  gemm_k<true, false, false, false><<<dim3(8, 8, CB), 256, 0, stream>>>(
      rm, rm, nullptr, covr, CN, CN, CT, CN, CN, CN, sTN, sTN, sPB, covscale);
  sds_k<<<32, 256, 0, stream>>>(covx, covr, sdx, sdr);
  ridge_k<<<(int)(SBNN / 256), 256, 0, stream>>>(covx, Lm);

  // blocked Cholesky (NB=64)
  for (int k = 0; k < 8; ++k) {
    chol_diag<<<CB, 256, 0, stream>>>(Lm, Winv, k);
    int Mt = CN - 64 * (k + 1);
    if (Mt > 0) {
      float* Apan = Lm + (size_t)(k + 1) * 64 * CN + k * 64;
      float* Atrl = Lm + (size_t)(k + 1) * 64 * CN + (k + 1) * 64;
      // panel: P <- P * Winv^T
      gemm_k<false, true, false, false><<<dim3(1, Mt / 64, CB), 256, 0, stream>>>(
          Apan, Winv, nullptr, Apan, Mt, 64, 64, CN, 64, CN, sPB, 4096LL, sPB, 1.0f);
      // trailing: A22 -= P * P^T
      gemm_k<false, true, true, false><<<dim3(Mt / 64, Mt / 64, CB), 256, 0, stream>>>(
          Apan, Apan, nullptr, Atrl, Mt, Mt, 64, CN, CN, CN, sPB, sPB, sPB, -1.0f);
    }
  }
  transpose_k<<<dim3(8, 8, CB), 256, 0, stream>>>(Lm, LTm);
  tri_fwd<<<dim3(64, CB), 512, 0, stream>>>(Lm, LTm, prY);
  tri_bwd<<<dim3(64, CB), 512, 0, stream>>>(Lm, prY);
  sdp_k<<<32, 256, 0, stream>>>(prY, sdp);

  // similarity -> alphas -> fused adjacency -> normalize
  fuse_sums<<<dim3(128, CB), 256, 0, stream>>>(covx, covr, prY, sdx, sdr, sdp, sums);
  alphas_k<<<1, 64, 0, stream>>>(sums, gam, alph);
  build_fused<<<dim3(1024, CB), 256, 0, stream>>>(covx, covr, prY, sdx, sdr, sdp, alph, Af);
  rowsum_k<<<CB * CN, 256, 0, stream>>>(Af, dinv);
  norm_adj_k<<<dim3(1024, CB), 256, 0, stream>>>(Af, dinv);

  // features + layernorm
  xbuild_k<<<dim3(CN, CB), 256, 0, stream>>>(covx, covr, prY, sdx, sdr, sdp, lng, lnb, Xn);

  // GCN: H = relu(Anorm @ (H @ W + b)) x3
  gemm_k<false, false, false, false><<<dim3(8, 128, 1), 256, 0, stream>>>(
      Xn, W0, b0, G, CB * CN, CD, CIN, CIN, CD, CD, 0, 0, 0, 1.0f);
  gemm_k<false, false, false, true><<<dim3(8, 8, CB), 256, 0, stream>>>(
      Af, G, nullptr, Ha, CN, CD, CN, CN, CD, CD, sPB, sND, sND, 1.0f);
  gemm_k<false, false, false, false><<<dim3(8, 128, 1), 256, 0, stream>>>(
      Ha, W1, b1, G, CB * CN, CD, CD, CD, CD, CD, 0, 0, 0, 1.0f);
  gemm_k<false, false, false, true><<<dim3(8, 8, CB), 256, 0, stream>>>(
      Af, G, nullptr, Hb, CN, CD, CN, CN, CD, CD, sPB, sND, sND, 1.0f);
  gemm_k<false, false, false, false><<<dim3(8, 128, 1), 256, 0, stream>>>(
      Hb, W2, b2, G, CB * CN, CD, CD, CD, CD, CD, 0, 0, 0, 1.0f);
  gemm_k<false, false, false, true><<<dim3(8, 8, CB), 256, 0, stream>>>(
      Af, G, nullptr, Ha, CN, CD, CN, CN, CD, CD, sPB, sND, sND, 1.0f);

  gmean_k<<<dim3(2, CB), 256, 0, stream>>>(Ha, gm);
  final_k<<<CB, 256, 0, stream>>>(gm, Wc, bc, out);
}

// Round 3
// 2954.336 us; speedup vs baseline: 1.2240x; 1.1050x over previous
//
#include <hip/hip_runtime.h>
#include <math.h>

#define EPSF 1e-8f

constexpr int CB = 16;      // batch
constexpr int CT = 1024;    // time
constexpr int CN = 512;     // nodes
constexpr int CD = 512;     // hidden
constexpr int CIN = 1536;   // 3*N
constexpr int PB = CN * CN;                 // 262144 per-batch matrix elems
constexpr size_t SBTN = (size_t)CB * CT * CN;   // 8,388,608
constexpr size_t SBNN = (size_t)CB * PB;        // 4,194,304

// ---------------- utility ----------------
__global__ void zero_k(float* p, int n) {
  int i = blockIdx.x * 256 + threadIdx.x;
  if (i < n) p[i] = 0.f;
}

// ---------------- column means + centering ----------------
__global__ __launch_bounds__(256) void colmean_k(const float* __restrict__ x, float* __restrict__ ms) {
  int b = blockIdx.y;
  int n = blockIdx.x * 256 + threadIdx.x;
  int t0 = blockIdx.z * 256;
  const float* xb = x + (size_t)b * CT * CN + (size_t)t0 * CN + n;
  float s = 0.f;
  for (int t = 0; t < 256; ++t) s += xb[(size_t)t * CN];
  atomicAdd(&ms[b * CN + n], s);
}

__global__ __launch_bounds__(256) void center_k(const float* __restrict__ x, const float* __restrict__ ms,
                                                float* __restrict__ xm) {
  size_t e = (size_t)blockIdx.x * 256 + threadIdx.x;
  int b = (int)(e >> 19);          // T*N = 2^19
  int n = (int)(e & (CN - 1));
  xm[e] = x[e] - ms[b * CN + n] * (1.0f / CT);
}

// ---------------- Spearman ranks via in-LDS bitonic sort ----------------
__global__ __launch_bounds__(256) void ranks_k(const float* __restrict__ x, float* __restrict__ rm) {
  int b = blockIdx.y;
  int n0 = blockIdx.x * 4;
  __shared__ unsigned int key[4][1032];
  __shared__ unsigned int idxs[4][1032];
  const float* xb = x + (size_t)b * CT * CN + n0;
  for (int t = threadIdx.x; t < 1024; t += 256) {
    float4 v = *(const float4*)&xb[(size_t)t * CN];
    float vv[4] = {v.x, v.y, v.z, v.w};
#pragma unroll
    for (int c = 0; c < 4; ++c) {
      unsigned int u = __float_as_uint(vv[c]);
      u = (u & 0x80000000u) ? ~u : (u | 0x80000000u);
      key[c][t] = u;
      idxs[c][t] = t;
    }
  }
  __syncthreads();
  const int c = threadIdx.x >> 6;       // one wave per column
  const int lane = threadIdx.x & 63;
  unsigned int* K = key[c];
  unsigned int* I = idxs[c];
  for (int k = 2; k <= 1024; k <<= 1) {
    for (int j = k >> 1; j >= 1; j >>= 1) {
#pragma unroll
      for (int m = 0; m < 8; ++m) {
        int t = m * 64 + lane;
        int i = 2 * t - (t & (j - 1));
        int l = i + j;
        unsigned int k1 = K[i], k2 = K[l];
        unsigned int i1 = I[i], i2 = I[l];
        bool gt = (k1 > k2) || (k1 == k2 && i1 > i2);
        bool up = ((i & k) == 0);
        if (gt == up) {
          K[i] = k2; K[l] = k1;
          I[i] = i2; I[l] = i1;
        }
      }
      __syncthreads();
    }
  }
#pragma unroll
  for (int m = 0; m < 16; ++m) {
    int p = m * 64 + lane;
    K[I[p]] = __float_as_uint((float)(p + 1) - 512.5f);
  }
  __syncthreads();
  float* rmb = rm + (size_t)b * CT * CN + n0;
  for (int t = threadIdx.x; t < 1024; t += 256) {
    float4 o;
    o.x = __uint_as_float(key[0][t]);
    o.y = __uint_as_float(key[1][t]);
    o.z = __uint_as_float(key[2][t]);
    o.w = __uint_as_float(key[3][t]);
    *(float4*)&rmb[(size_t)t * CN] = o;
  }
}

// ---------------- generic fp32 tiled GEMM ----------------
// C = alpha * op(A) * op(B) [+ C if ACC] [+ bias] [relu]
// TA: A stored (K x M) row-major. TB: B stored (N x K) row-major.
// SYRK: skip k-blocks < max(m0,n0) (for W^T W with lower-triangular W).
template<bool TA, bool TB, bool ACC, bool RELU, bool SYRK = false>
__global__ __launch_bounds__(256) void gemm_k(
    const float* __restrict__ A, const float* __restrict__ B,
    const float* __restrict__ bias, float* __restrict__ C,
    int M, int Nc, int K, int lda, int ldb, int ldc,
    long long sA, long long sB, long long sC, float alpha) {
  __shared__ float As[16][68];
  __shared__ float Bs[16][68];
  const int bz = blockIdx.z;
  A += (size_t)bz * sA;
  B += (size_t)bz * sB;
  C += (size_t)bz * sC;
  const int n0 = blockIdx.x * 64;
  const int m0 = blockIdx.y * 64;
  const int tid = threadIdx.x;
  const int tn = (tid & 15) * 4;
  const int tm = (tid >> 4) * 4;
  float acc[4][4];
#pragma unroll
  for (int i = 0; i < 4; ++i)
#pragma unroll
    for (int j = 0; j < 4; ++j) acc[i][j] = 0.f;

  const int kbeg = SYRK ? (m0 > n0 ? m0 : n0) : 0;
  for (int k0 = kbeg; k0 < K; k0 += 16) {
    if (TA) {
      const int lk = tid >> 4;
      const int lm = (tid & 15) * 4;
      const float4 v = *(const float4*)&A[(size_t)(k0 + lk) * lda + m0 + lm];
      *(float4*)&As[lk][lm] = v;
    } else {
      const int lm = tid >> 2;
      const int lk = (tid & 3) * 4;
      const float4 v = *(const float4*)&A[(size_t)(m0 + lm) * lda + k0 + lk];
      As[lk + 0][lm] = v.x; As[lk + 1][lm] = v.y; As[lk + 2][lm] = v.z; As[lk + 3][lm] = v.w;
    }
    if (TB) {
      const int ln = tid >> 2;
      const int lk = (tid & 3) * 4;
      const float4 v = *(const float4*)&B[(size_t)(n0 + ln) * ldb + k0 + lk];
      Bs[lk + 0][ln] = v.x; Bs[lk + 1][ln] = v.y; Bs[lk + 2][ln] = v.z; Bs[lk + 3][ln] = v.w;
    } else {
      const int lk = tid >> 4;
      const int ln = (tid & 15) * 4;
      const float4 v = *(const float4*)&B[(size_t)(k0 + lk) * ldb + n0 + ln];
      *(float4*)&Bs[lk][ln] = v;
    }
    __syncthreads();
#pragma unroll
    for (int kk = 0; kk < 16; ++kk) {
      const float4 a4 = *(const float4*)&As[kk][tm];
      const float4 b4 = *(const float4*)&Bs[kk][tn];
      const float av[4] = {a4.x, a4.y, a4.z, a4.w};
      const float bv[4] = {b4.x, b4.y, b4.z, b4.w};
#pragma unroll
      for (int i = 0; i < 4; ++i)
#pragma unroll
        for (int j = 0; j < 4; ++j) acc[i][j] = fmaf(av[i], bv[j], acc[i][j]);
    }
    __syncthreads();
  }
  float4 bb = make_float4(0.f, 0.f, 0.f, 0.f);
  if (bias) bb = *(const float4*)&bias[n0 + tn];
#pragma unroll
  for (int i = 0; i < 4; ++i) {
    size_t off = (size_t)(m0 + tm + i) * ldc + (n0 + tn);
    float4 v;
    v.x = alpha * acc[i][0] + bb.x;
    v.y = alpha * acc[i][1] + bb.y;
    v.z = alpha * acc[i][2] + bb.z;
    v.w = alpha * acc[i][3] + bb.w;
    if (ACC) {
      const float4 c0 = *(const float4*)&C[off];
      v.x += c0.x; v.y += c0.y; v.z += c0.z; v.w += c0.w;
    }
    if (RELU) {
      v.x = fmaxf(v.x, 0.f); v.y = fmaxf(v.y, 0.f);
      v.z = fmaxf(v.z, 0.f); v.w = fmaxf(v.w, 0.f);
    }
    *(float4*)&C[off] = v;
  }
}

// ---------------- std vectors ----------------
__global__ void sds_k(const float* __restrict__ covx, const float* __restrict__ covr,
                      float* __restrict__ sdx, float* __restrict__ sdr) {
  int idx = blockIdx.x * 256 + threadIdx.x;     // < CB*CN
  int b = idx >> 9, i = idx & (CN - 1);
  size_t off = (size_t)b * PB + (size_t)i * (CN + 1);
  sdx[idx] = sqrtf(fmaxf(covx[off], EPSF));
  sdr[idx] = sqrtf(fmaxf(covr[off], EPSF));
}

__global__ void ridge_k(const float* __restrict__ covx, float* __restrict__ A) {
  size_t e = (size_t)blockIdx.x * 256 + threadIdx.x;  // < SBNN
  int ij = (int)(e & (PB - 1));
  int i = ij >> 9, j = ij & (CN - 1);
  A[e] = covx[e] + ((i == j) ? 0.001f : 0.0f);
}

// in-place: covx -> Pearson corr, covr -> Spearman corr (diag = 1)
__global__ __launch_bounds__(256) void normPS_k(float* __restrict__ covx, float* __restrict__ covr,
                                                const float* __restrict__ sdx, const float* __restrict__ sdr) {
  int b = blockIdx.y;
  int e = blockIdx.x * 256 + threadIdx.x;
  int i = e >> 9, j = e & (CN - 1);
  size_t off = (size_t)b * PB + e;
  if (i == j) {
    covx[off] = 1.0f;
    covr[off] = 1.0f;
  } else {
    covx[off] = covx[off] / (sdx[b * CN + i] * sdx[b * CN + j]);
    covr[off] = covr[off] / (sdr[b * CN + i] * sdr[b * CN + j]);
  }
}

// ---------------- blocked Cholesky pieces ----------------
// factor 64x64 diagonal block in LDS; store Winv_k = L11^{-1} for ALL k
__global__ __launch_bounds__(256) void chol_diag(float* __restrict__ A, float* __restrict__ Winv8, int kstep) {
  int b = blockIdx.x;
  float* Ab = A + (size_t)b * PB + (size_t)(kstep * 64) * CN + kstep * 64;
  __shared__ float Ds[64][65];
  __shared__ float Ws[64][65];
  int tid = threadIdx.x;
  for (int idx = tid; idx < 4096; idx += 256) {
    int j = idx >> 6, l = idx & 63;
    Ds[j][l] = Ab[(size_t)j * CN + l];
    Ws[j][l] = (j == l) ? 1.f : 0.f;
  }
  __syncthreads();
  for (int i = 0; i < 64; ++i) {
    float dii = Ds[i][i];
    float lii = sqrtf(dii);
    float rinv = 1.0f / lii;
    __syncthreads();
    if (tid < 64) {
      if (tid > i) Ds[tid][i] *= rinv;
      else if (tid == i) Ds[i][i] = lii;
    }
    __syncthreads();
    for (int idx = tid; idx < 4096; idx += 256) {
      int j = idx >> 6, l = idx & 63;
      if (l > i && j >= l) Ds[j][l] -= Ds[j][i] * Ds[l][i];
    }
    __syncthreads();
  }
  // Ws = L^{-1} (forward substitution, update form)
  for (int i = 0; i < 64; ++i) {
    if (tid < 64) Ws[i][tid] = Ws[i][tid] / Ds[i][i];
    __syncthreads();
    for (int idx = tid; idx < 4096; idx += 256) {
      int j = idx >> 6, l = idx & 63;
      if (j > i) Ws[j][l] -= Ds[j][i] * Ws[i][l];
    }
    __syncthreads();
  }
  for (int idx = tid; idx < 4096; idx += 256) {
    int j = idx >> 6, l = idx & 63;
    Ab[(size_t)j * CN + l] = Ds[j][l];
    Winv8[(size_t)b * 32768 + (size_t)kstep * 4096 + idx] = Ws[j][l];
  }
}

// copy all diagonal-block inverses into W
__global__ void wdiag_k(const float* __restrict__ Winv8, float* __restrict__ W) {
  int e = blockIdx.x * 256 + threadIdx.x;   // < 524288
  int b = e >> 15;
  int r = e & 32767;
  int blk = r >> 12;
  int idx = r & 4095;
  int row = idx >> 6, col = idx & 63;
  W[(size_t)b * PB + (size_t)(blk * 64 + row) * CN + blk * 64 + col] = Winv8[e];
}

__global__ void sdp_k(const float* __restrict__ prec, float* __restrict__ sdp) {
  int idx = blockIdx.x * 256 + threadIdx.x;
  int b = idx >> 9, i = idx & (CN - 1);
  sdp[idx] = sqrtf(fmaxf(prec[(size_t)b * PB + (size_t)i * (CN + 1)], EPSF));
}

// in-place: prec -> tanh'd partial-corr matrix (diag = tanh(1))
__global__ __launch_bounds__(256) void pc_k(float* __restrict__ prec, const float* __restrict__ sdp) {
  int b = blockIdx.y;
  int e = blockIdx.x * 256 + threadIdx.x;
  int i = e >> 9, j = e & (CN - 1);
  size_t off = (size_t)b * PB + e;
  float arg = (i == j) ? 1.0f : -prec[off] / (sdp[b * CN + i] * sdp[b * CN + j]);
  prec[off] = tanhf(arg);
}

// ---------------- similarity sums over strict upper triangle ----------------
__global__ __launch_bounds__(256) void fuse_sums(const float* __restrict__ Pm, const float* __restrict__ Sm,
                                                 const float* __restrict__ Cm, float* __restrict__ sums) {
  int b = blockIdx.y;
  int base = blockIdx.x * 2048;
  float pp = 0, ss = 0, cc = 0, ps = 0, pc = 0, sc = 0;
  for (int u = 0; u < 8; ++u) {
    int e = base + u * 256 + threadIdx.x;
    int i = e >> 9, j = e & (CN - 1);
    if (j > i) {
      size_t off = (size_t)b * PB + e;
      float p = Pm[off];
      float s = Sm[off];
      float cv = Cm[off];
      pp += p * p; ss += s * s; cc += cv * cv;
      ps += p * s; pc += p * cv; sc += s * cv;
    }
  }
  __shared__ float red[256];
  float vals[6] = {pp, ss, cc, ps, pc, sc};
#pragma unroll
  for (int v = 0; v < 6; ++v) {
    red[threadIdx.x] = vals[v];
    __syncthreads();
    for (int s2 = 128; s2 > 0; s2 >>= 1) {
      if (threadIdx.x < s2) red[threadIdx.x] += red[threadIdx.x + s2];
      __syncthreads();
    }
    if (threadIdx.x == 0) atomicAdd(&sums[b * 6 + v], red[0]);
    __syncthreads();
  }
}

__global__ void alphas_k(const float* __restrict__ sums, const float* __restrict__ gamma,
                         float* __restrict__ alph) {
  int b = threadIdx.x;
  if (b >= CB) return;
  float sPP = sums[b * 6 + 0], sSS = sums[b * 6 + 1], sCC = sums[b * 6 + 2];
  float sPS = sums[b * 6 + 3], sPC = sums[b * 6 + 4], sSC = sums[b * 6 + 5];
  float numP = 0.5f * (sPS + sPC), numS = 0.5f * (sPS + sSC), numC = 0.5f * (sPC + sSC);
  float noP = 0.5f * sqrtf(sSS + sCC + 2.f * sSC);
  float noS = 0.5f * sqrtf(sPP + sCC + 2.f * sPC);
  float noC = 0.5f * sqrtf(sPP + sSS + 2.f * sPS);
  float dP = fmaxf(sqrtf(sPP), EPSF) * fmaxf(noP, EPSF);
  float dS = fmaxf(sqrtf(sSS), EPSF) * fmaxf(noS, EPSF);
  float dC = fmaxf(sqrtf(sCC), EPSF) * fmaxf(noC, EPSF);
  float g = gamma[0];
  float aP = g * numP / dP, aS = g * numS / dS, aC = g * numC / dC;
  float m = fmaxf(fmaxf(aP, aS), aC);
  float eP = expf(aP - m), eS = expf(aS - m), eC = expf(aC - m);
  float inv = 1.f / (eP + eS + eC);
  alph[b * 3 + 0] = eP * inv;
  alph[b * 3 + 1] = eS * inv;
  alph[b * 3 + 2] = eC * inv;
}

// ---------------- A_fused (symmetrized, unit diag) ----------------
__global__ __launch_bounds__(256) void build_fused(const float* __restrict__ Pm, const float* __restrict__ Sm,
                                                   const float* __restrict__ Cm, const float* __restrict__ alph,
                                                   float* __restrict__ Af) {
  int b = blockIdx.y;
  int e = blockIdx.x * 256 + threadIdx.x;   // < PB
  int i = e >> 9, j = e & (CN - 1);
  size_t off = (size_t)b * PB + e;
  float v;
  if (i == j) {
    v = 1.0f;
  } else {
    v = alph[b * 3 + 0] * Pm[off] + alph[b * 3 + 1] * Sm[off] + alph[b * 3 + 2] * Cm[off];
  }
  Af[off] = v;
}

__global__ __launch_bounds__(256) void rowsum_k(const float* __restrict__ Af, float* __restrict__ dinv) {
  int row = blockIdx.x;   // b*CN + i
  const float* r = Af + (size_t)row * CN;
  __shared__ float red[256];
  red[threadIdx.x] = r[threadIdx.x] + r[threadIdx.x + 256];
  __syncthreads();
  for (int s = 128; s > 0; s >>= 1) {
    if (threadIdx.x < s) red[threadIdx.x] += red[threadIdx.x + s];
    __syncthreads();
  }
  if (threadIdx.x == 0) dinv[row] = 1.0f / sqrtf(fmaxf(red[0], EPSF));
}

__global__ __launch_bounds__(256) void norm_adj_k(float* __restrict__ Af, const float* __restrict__ dinv) {
  int b = blockIdx.y;
  int e = blockIdx.x * 256 + threadIdx.x;
  int i = e >> 9, j = e & (CN - 1);
  Af[(size_t)b * PB + e] *= dinv[b * CN + i] * dinv[b * CN + j];
}

// ---------------- X features + LayerNorm ----------------
__global__ __launch_bounds__(256) void xbuild_k(const float* __restrict__ Pm, const float* __restrict__ Sm,
                                                const float* __restrict__ Cm,
                                                const float* __restrict__ lng, const float* __restrict__ lnb,
                                                float* __restrict__ Xn) {
  int b = blockIdx.y, n = blockIdx.x;
  __shared__ float vals[CIN];
  __shared__ float rs[256], rq[256];
  const float* rows[3] = {Pm + (size_t)b * PB + (size_t)n * CN,
                          Sm + (size_t)b * PB + (size_t)n * CN,
                          Cm + (size_t)b * PB + (size_t)n * CN};
  float ls = 0.f, lq = 0.f;
#pragma unroll
  for (int k = 0; k < 6; ++k) {
    int pos = k * 256 + threadIdx.x;
    int part = pos >> 9;
    int j = pos & (CN - 1);
    float v = rows[part][j];
    vals[pos] = v;
    ls += v; lq += v * v;
  }
  rs[threadIdx.x] = ls; rq[threadIdx.x] = lq;
  __syncthreads();
  for (int s = 128; s > 0; s >>= 1) {
    if (threadIdx.x < s) { rs[threadIdx.x] += rs[threadIdx.x + s]; rq[threadIdx.x] += rq[threadIdx.x + s]; }
    __syncthreads();
  }
  float mu = rs[0] * (1.0f / CIN);
  float var = rq[0] * (1.0f / CIN) - mu * mu;
  float rstd = 1.0f / sqrtf(var + 1e-5f);
  float* Xrow = Xn + ((size_t)b * CN + n) * CIN;
#pragma unroll
  for (int k = 0; k < 6; ++k) {
    int pos = k * 256 + threadIdx.x;
    Xrow[pos] = (vals[pos] - mu) * rstd * lng[pos] + lnb[pos];
  }
}

// ---------------- head ----------------
__global__ __launch_bounds__(256) void gmean_k(const float* __restrict__ H, float* __restrict__ gm) {
  int b = blockIdx.y;
  int d = blockIdx.x * 256 + threadIdx.x;
  const float* Hb = H + (size_t)b * CN * CD + d;
  float s = 0.f;
  for (int n = 0; n < CN; ++n) s += Hb[(size_t)n * CD];
  gm[b * CD + d] = s * (1.0f / CN);
}

__global__ __launch_bounds__(256) void final_k(const float* __restrict__ gm, const float* __restrict__ Wc,
                                               const float* __restrict__ bc, float* __restrict__ out) {
  int b = blockIdx.x;
  __shared__ float red[256];
  float s = gm[b * CD + threadIdx.x] * Wc[threadIdx.x] +
            gm[b * CD + 256 + threadIdx.x] * Wc[256 + threadIdx.x];
  red[threadIdx.x] = s;
  __syncthreads();
  for (int k = 128; k > 0; k >>= 1) {
    if (threadIdx.x < k) red[threadIdx.x] += red[threadIdx.x + k];
    __syncthreads();
  }
  if (threadIdx.x == 0) {
    float z = red[0] + bc[0];
    out[b] = 1.0f / (1.0f + expf(-z));
  }
}

// ---------------- launcher ----------------
extern "C" void kernel_launch(void* const* d_in, const int* in_sizes, int n_in,
                              void* d_out, int out_size, void* d_ws, size_t ws_size,
                              hipStream_t stream) {
  const float* x    = (const float*)d_in[0];
  const float* gam  = (const float*)d_in[1];
  const float* lng  = (const float*)d_in[2];
  const float* lnb  = (const float*)d_in[3];
  const float* W0   = (const float*)d_in[4];
  const float* b0   = (const float*)d_in[5];
  const float* W1   = (const float*)d_in[6];
  const float* b1   = (const float*)d_in[7];
  const float* W2   = (const float*)d_in[8];
  const float* b2   = (const float*)d_in[9];
  const float* Wc   = (const float*)d_in[10];
  const float* bc   = (const float*)d_in[11];
  float* out = (float*)d_out;
  float* ws = (float*)d_ws;

  // workspace layout (floats). region A [0, 16777216): xm+rm early,
  // Winv8+Ttmp mid (after cov GEMMs), Xn+Af late.
  float* xm    = ws;
  float* rm    = ws + SBTN;
  float* Winv8 = ws;                      // 16*8*4096 = 524288 (xm dead)
  float* Ttmp  = ws + 524288;             // 16*64*512 = 524288
  float* Xn    = ws;                      // reuse at xbuild time
  float* Af    = ws + 12582912;           // 16*512*1536 .. 16777216
  float* covx  = ws + 16777216;           // -> Pearson corr in place
  float* covr  = covx + SBNN;             // -> Spearman corr in place
  float* Lm    = covx + 2 * SBNN;
  float* Wtri  = covx + 3 * SBNN;         // W = L^{-1}
  float* prY   = covx + 4 * SBNN;         // prec -> tanh'd partial corr
  float* sdx   = covx + 5 * SBNN;
  float* sdr   = sdx + 8192;
  float* sdp   = sdr + 8192;
  float* dinv  = sdp + 8192;
  float* gm    = dinv + 8192;
  float* ms    = gm + 8192;
  float* sums  = ms + 8192;
  float* alph  = sums + 96;
  // GCN buffer reuse (all dead by then):
  float* G  = Lm;
  float* Ha = Wtri;
  float* Hb = prY;

  const float covscale = (float)(1.0 / 1023.00000001);
  const long long sTN = (long long)CT * CN;
  const long long sPB = (long long)PB;
  const long long sND = (long long)CN * CD;

  // means + centering + ranks
  zero_k<<<(8288 + 255) / 256, 256, 0, stream>>>(ms, 8288);   // ms + sums
  colmean_k<<<dim3(2, CB, 4), 256, 0, stream>>>(x, ms);
  center_k<<<(int)(SBTN / 256), 256, 0, stream>>>(x, ms, xm);
  ranks_k<<<dim3(CN / 4, CB), 256, 0, stream>>>(x, rm);

  // covariances (syrk, K=1024)
  gemm_k<true, false, false, false><<<dim3(8, 8, CB), 256, 0, stream>>>(
      xm, xm, nullptr, covx, CN, CN, CT, CN, CN, CN, sTN, sTN, sPB, covscale);
  gemm_k<true, false, false, false><<<dim3(8, 8, CB), 256, 0, stream>>>(
      rm, rm, nullptr, covr, CN, CN, CT, CN, CN, CN, sTN, sTN, sPB, covscale);
  sds_k<<<32, 256, 0, stream>>>(covx, covr, sdx, sdr);
  ridge_k<<<(int)(SBNN / 256), 256, 0, stream>>>(covx, Lm);
  zero_k<<<(int)(SBNN / 256), 256, 0, stream>>>(Wtri, (int)SBNN);
  // covx/covr -> correlation matrices in place (after ridge copy)
  normPS_k<<<dim3(1024, CB), 256, 0, stream>>>(covx, covr, sdx, sdr);

  // blocked Cholesky (NB=64), keeping all diagonal-block inverses
  for (int k = 0; k < 8; ++k) {
    chol_diag<<<CB, 256, 0, stream>>>(Lm, Winv8, k);
    int Mt = CN - 64 * (k + 1);
    if (Mt > 0) {
      float* Apan = Lm + (size_t)(k + 1) * 64 * CN + k * 64;
      float* Atrl = Lm + (size_t)(k + 1) * 64 * CN + (k + 1) * 64;
      // panel: P <- P * Winv_k^T
      gemm_k<false, true, false, false><<<dim3(1, Mt / 64, CB), 256, 0, stream>>>(
          Apan, Winv8 + (size_t)k * 4096, nullptr, Apan, Mt, 64, 64, CN, 64, CN, sPB, 32768LL, sPB, 1.0f);
      // trailing: A22 -= P * P^T
      gemm_k<false, true, true, false><<<dim3(Mt / 64, Mt / 64, CB), 256, 0, stream>>>(
          Apan, Apan, nullptr, Atrl, Mt, Mt, 64, CN, CN, CN, sPB, sPB, sPB, -1.0f);
    }
  }

  // W = L^{-1} (blocked, row-block by row-block)
  wdiag_k<<<2048, 256, 0, stream>>>(Winv8, Wtri);
  for (int i = 1; i < 8; ++i) {
    int Kw = i * 64;
    // T = L[i-row-block, 0:Kw] * W[0:Kw, 0:Kw]
    gemm_k<false, false, false, false><<<dim3(i, 1, CB), 256, 0, stream>>>(
        Lm + (size_t)i * 64 * CN, Wtri, nullptr, Ttmp,
        64, Kw, Kw, CN, CN, 512, sPB, sPB, 32768LL, 1.0f);
    // W[i-row-block, 0:Kw] = -Winv_i * T
    gemm_k<false, false, false, false><<<dim3(i, 1, CB), 256, 0, stream>>>(
        Winv8 + (size_t)i * 4096, Ttmp, nullptr, Wtri + (size_t)i * 64 * CN,
        64, Kw, 64, 64, 512, CN, 32768LL, 32768LL, sPB, -1.0f);
  }

  // prec = W^T W (SYRK: W lower-triangular, start k at max(m0,n0))
  gemm_k<true, false, false, false, true><<<dim3(8, 8, CB), 256, 0, stream>>>(
      Wtri, Wtri, nullptr, prY, CN, CN, CN, CN, CN, CN, sPB, sPB, sPB, 1.0f);
  sdp_k<<<32, 256, 0, stream>>>(prY, sdp);
  pc_k<<<dim3(1024, CB), 256, 0, stream>>>(prY, sdp);

  // similarity -> alphas -> fused adjacency -> normalize
  fuse_sums<<<dim3(128, CB), 256, 0, stream>>>(covx, covr, prY, sums);
  alphas_k<<<1, 64, 0, stream>>>(sums, gam, alph);
  build_fused<<<dim3(1024, CB), 256, 0, stream>>>(covx, covr, prY, alph, Af);
  rowsum_k<<<CB * CN, 256, 0, stream>>>(Af, dinv);
  norm_adj_k<<<dim3(1024, CB), 256, 0, stream>>>(Af, dinv);

  // features + layernorm
  xbuild_k<<<dim3(CN, CB), 256, 0, stream>>>(covx, covr, prY, lng, lnb, Xn);

  // GCN: H = relu(Anorm @ (H @ W + b)) x3
  gemm_k<false, false, false, false><<<dim3(8, 128, 1), 256, 0, stream>>>(
      Xn, W0, b0, G, CB * CN, CD, CIN, CIN, CD, CD, 0, 0, 0, 1.0f);
  gemm_k<false, false, false, true><<<dim3(8, 8, CB), 256, 0, stream>>>(
      Af, G, nullptr, Ha, CN, CD, CN, CN, CD, CD, sPB, sND, sND, 1.0f);
  gemm_k<false, false, false, false><<<dim3(8, 128, 1), 256, 0, stream>>>(
      Ha, W1, b1, G, CB * CN, CD, CD, CD, CD, CD, 0, 0, 0, 1.0f);
  gemm_k<false, false, false, true><<<dim3(8, 8, CB), 256, 0, stream>>>(
      Af, G, nullptr, Hb, CN, CD, CN, CN, CD, CD, sPB, sND, sND, 1.0f);
  gemm_k<false, false, false, false><<<dim3(8, 128, 1), 256, 0, stream>>>(
      Hb, W2, b2, G, CB * CN, CD, CD, CD, CD, CD, 0, 0, 0, 1.0f);
  gemm_k<false, false, false, true><<<dim3(8, 8, CB), 256, 0, stream>>>(
      Af, G, nullptr, Ha, CN, CD, CN, CN, CD, CD, sPB, sND, sND, 1.0f);

  gmean_k<<<dim3(2, CB), 256, 0, stream>>>(Ha, gm);
  final_k<<<CB, 256, 0, stream>>>(gm, Wc, bc, out);
}